// Round 10
// baseline (819.093 us; speedup 1.0000x reference)
//
#include <hip/hip_runtime.h>
#include <hip/hip_fp16.h>
#include <cstdint>
#include <cstddef>

#define NN 100000
#define NE 1600000
#define HID 128
#define BN_EPS 1e-5f
#define NB_SCAN 98  // ceil(100000/1024)
#define BM2 128
#define NBLK2 ((NN + BM2 - 1) / BM2)  // 782 gemm blocks
#define NBC  ((NN + 255) / 256)       // 391 count blocks
#define SC_CHUNKS 256
#define SC_RANGE (NN / 8)             // 12500
#define SC_EPC (NE / SC_CHUNKS)       // 6250

typedef __attribute__((ext_vector_type(8))) short bf16x8;
typedef __attribute__((ext_vector_type(8))) _Float16 f16x8;
typedef __attribute__((ext_vector_type(4))) float f32x4;

// ---------------- workspace layout (bytes) ----------------
static constexpr size_t SZ_NODE = (size_t)NN * HID * 4;            // 51.2 MB
static constexpr size_t SZ_H16  = (size_t)NN * HID * 2;            // 25.6 MB
static constexpr size_t OFF_P   = 0;                               // h1 fp16 + h2 fp16
static constexpr size_t OFF_Q   = SZ_NODE;                         // z/u/v in-place chain (fp32)
static constexpr size_t OFF_R   = 2 * SZ_NODE;                     // part (0.8MB) then h3 fp16
static constexpr size_t OFF_CSR = 3 * SZ_NODE;
static constexpr size_t OFF_RP  = OFF_CSR + (size_t)NE * 4;
static constexpr size_t OFF_ZZ  = ((OFF_RP + (size_t)(NN + 1) * 4 + 255) / 256) * 256;
static constexpr size_t OFF_CNT = OFF_ZZ;
static constexpr size_t OFF_BS  = OFF_CNT + (((size_t)NN * 4 + 255) / 256) * 256;
static constexpr size_t OFF_FLG = OFF_BS + 512;
static constexpr size_t OFF_SS  = OFF_FLG + 256;                   // 5 x 256 f32 atomic sums
static constexpr size_t OFF_SCT = OFF_SS + 5 * 256 * 4;            // 5 int counters
static constexpr size_t ZZ_END  = ((OFF_SCT + 5 * 4 + 255) / 256) * 256;
static constexpr size_t ZZ_BYTES = ZZ_END - OFF_ZZ;
static constexpr size_t OFF_AC  = ZZ_END;                          // 6 x 256 f32 (bn a/c)
static constexpr size_t OFF_E   = OFF_AC + 6 * 256 * 4;            // ee: e0,e1,r0,r1 = 512 f32
static constexpr size_t OFF_WSP = OFF_E + 512 * 4;                 // 8 mats x [2][128][128] shorts
static constexpr size_t WS_NEEDED = OFF_WSP + (size_t)8 * 2 * HID * HID * 2;

// ---------------- helpers ----------------
__device__ __forceinline__ unsigned short f2bf(float f) {
  unsigned u = __float_as_uint(f);
  unsigned r = (u + 0x7fffu + ((u >> 16) & 1u)) >> 16;
  return (unsigned short)r;
}
__device__ __forceinline__ float bf2f(unsigned short b) {
  return __uint_as_float(((unsigned)b) << 16);
}
__device__ __forceinline__ int edge_at(const int* __restrict__ E, int f, int idx) {
  return f ? E[2 * (long long)idx] : E[idx];
}

// ---------------- dtype detection ----------------
__global__ void k_detect(const int* __restrict__ E, int* __restrict__ flag) {
  if (threadIdx.x == 0 && blockIdx.x == 0) {
    int f = 1;
    for (int i = 1; i < 256; i += 2)
      if (E[i] != 0) { f = 0; break; }
    *flag = f;
  }
}

// ---------------- CSR build (XCD-bucketed: rounds 6/8 verified) ----------------
__global__ __launch_bounds__(256) void k_hist(const int* __restrict__ E,
                                              const int* __restrict__ flag,
                                              int* __restrict__ cnt) {
  const int f = *flag;
  const int r = blockIdx.x & 7;
  const int chunk = blockIdx.x >> 3;
  const int lo = r * SC_RANGE, hi = lo + SC_RANGE;
  const int ebeg = chunk * SC_EPC, eend = ebeg + SC_EPC;
  for (int e = ebeg + threadIdx.x; e < eend; e += 256) {
    int d = edge_at(E, f, NE + e);
    d = min(max(d, 0), NN - 1);
    if (d >= lo && d < hi) atomicAdd(&cnt[d], 1);
  }
}

__global__ __launch_bounds__(256) void k_scan1(const int* __restrict__ cnt,
                                               int* __restrict__ rp,
                                               int* __restrict__ bs) {
  __shared__ int s[256];
  const int tid = threadIdx.x;
  const int base = blockIdx.x * 1024 + tid * 4;
  int v0 = 0, v1 = 0, v2 = 0, v3 = 0;
  if (base + 0 < NN) v0 = cnt[base + 0];
  if (base + 1 < NN) v1 = cnt[base + 1];
  if (base + 2 < NN) v2 = cnt[base + 2];
  if (base + 3 < NN) v3 = cnt[base + 3];
  const int t0 = v0, t1 = t0 + v1, t2 = t1 + v2, t3 = t2 + v3;
  s[tid] = t3;
  __syncthreads();
  for (int off = 1; off < 256; off <<= 1) {
    int xv = 0;
    if (tid >= off) xv = s[tid - off];
    __syncthreads();
    if (tid >= off) s[tid] += xv;
    __syncthreads();
  }
  const int excl = tid ? s[tid - 1] : 0;
  if (base + 0 < NN) rp[base + 0] = excl;
  if (base + 1 < NN) rp[base + 1] = excl + t0;
  if (base + 2 < NN) rp[base + 2] = excl + t1;
  if (base + 3 < NN) rp[base + 3] = excl + t2;
  if (tid == 255) bs[blockIdx.x] = s[255];
}

__global__ __launch_bounds__(128) void k_scan2(int* __restrict__ bs) {
  __shared__ int s[128];
  const int tid = threadIdx.x;
  s[tid] = (tid < NB_SCAN) ? bs[tid] : 0;
  __syncthreads();
  for (int off = 1; off < 128; off <<= 1) {
    int xv = 0;
    if (tid >= off) xv = s[tid - off];
    __syncthreads();
    if (tid >= off) s[tid] += xv;
    __syncthreads();
  }
  if (tid < NB_SCAN) bs[tid] = tid ? s[tid - 1] : 0;
}

__global__ __launch_bounds__(256) void k_scan3(int* __restrict__ rp,
                                               const int* __restrict__ bs,
                                               int* __restrict__ cursor) {
  const int off = bs[blockIdx.x];
  const int base = blockIdx.x * 1024 + threadIdx.x * 4;
  #pragma unroll
  for (int j = 0; j < 4; ++j) {
    const int i = base + j;
    if (i < NN) {
      const int v = rp[i] + off;
      rp[i] = v;
      cursor[i] = v;
    }
  }
  if (blockIdx.x == 0 && threadIdx.x == 0) rp[NN] = NE;
}

// scatter embeds x[src] in csr bit31 (round-9 verified)
__global__ __launch_bounds__(256) void k_scatter(const int* __restrict__ E,
                                                 const int* __restrict__ flag,
                                                 const int* __restrict__ x,
                                                 int* __restrict__ cursor,
                                                 int* __restrict__ csr) {
  const int f = *flag;
  const int r = blockIdx.x & 7;
  const int chunk = blockIdx.x >> 3;
  const int lo = r * SC_RANGE, hi = lo + SC_RANGE;
  const int ebeg = chunk * SC_EPC, eend = ebeg + SC_EPC;
  for (int e = ebeg + threadIdx.x; e < eend; e += 256) {
    int d = edge_at(E, f, NE + e);
    d = min(max(d, 0), NN - 1);
    if (d >= lo && d < hi) {
      int s = edge_at(E, f, e);
      s = min(max(s, 0), NN - 1);
      const int xb = x[s] & 1;
      const int pos = atomicAdd(&cursor[d], 1);
      if ((unsigned)pos < (unsigned)NE) csr[pos] = s | (xb << 31);
    }
  }
}

// ---------------- weight pre-split ----------------
// slots 0-4 (layer GEMMs, bf16 hi/lo): 0=W2[0] 1=W1[1] 2=W2[1] 3=W1[2] 4=W2[2]
// slots 5-7 (rdgemm, fp16 hi at +0; lo plane unused now): 5=rW1[1] 6=rW1[2] 7=rW1[3]
__global__ __launch_bounds__(256) void k_prepw(const float* __restrict__ W1,
                                               const float* __restrict__ W2,
                                               const float* __restrict__ rW1,
                                               short* __restrict__ wsp) {
  const int g = blockIdx.x * 256 + threadIdx.x;
  const int m = g >> 14, idx = g & 16383;
  const int k = idx >> 7, n = idx & 127;
  const float* src;
  switch (m) {
    case 0: src = W2; break;
    case 1: src = W1 + 1 * HID * HID; break;
    case 2: src = W2 + 1 * HID * HID; break;
    case 3: src = W1 + 2 * HID * HID; break;
    case 4: src = W2 + 2 * HID * HID; break;
    case 5: src = rW1 + 1 * HID * HID; break;
    case 6: src = rW1 + 2 * HID * HID; break;
    default: src = rW1 + 3 * HID * HID; break;
  }
  const float v = src[k * HID + n];
  short* dst = wsp + (size_t)m * 32768;
  if (m < 5) {
    const unsigned short hb = f2bf(v);
    dst[n * HID + k] = (short)hb;
    dst[16384 + n * HID + k] = (short)f2bf(v - bf2f(hb));
  } else {
    const __half hh = __float2half_rn(v);
    dst[n * HID + k] = (short)__half_as_ushort(hh);
    dst[16384 + n * HID + k] = 0;
  }
}

// ---------------- layer-1 rank-2 shortcut ----------------
__global__ __launch_bounds__(256) void k_prep(const float* __restrict__ emb,
                                              const float* __restrict__ W1,
                                              const float* __restrict__ rW1,
                                              float* __restrict__ ee) {
  const int t = threadIdx.x;
  const int f = t & 127;
  const float* er = emb + (t >> 7) * HID;
  float se = 0.f, sr = 0.f;
  for (int k = 0; k < HID; ++k) {
    const float ev = er[k];
    se = fmaf(ev, W1[k * HID + f], se);
    sr = fmaf(ev, rW1[k * HID + f], sr);
  }
  ee[t] = se;        // e0,e1
  ee[256 + t] = sr;  // r0,r1
}

// per-node class counts from LINEAR csr read (x-bit in bit31)
__global__ __launch_bounds__(256) void k_cnt(const int* __restrict__ x,
                                             const int* __restrict__ rp,
                                             const int* __restrict__ csr,
                                             int* __restrict__ a01,
                                             float* __restrict__ momp) {
  const int n = blockIdx.x * 256 + threadIdx.x;
  float m[5] = {0.f, 0.f, 0.f, 0.f, 0.f};
  if (n < NN) {
    const int beg = rp[n], end = rp[n + 1];
    int c1 = 0;
    for (int j = beg; j < end; ++j) c1 += (int)(((unsigned)csr[j]) >> 31);
    const int a1 = c1 + (x[n] & 1);
    const int a0 = (end - beg + 1) - a1;
    a01[n] = a0 | (a1 << 16);
    m[0] = (float)a0;
    m[1] = (float)a1;
    m[2] = (float)a0 * (float)a0;
    m[3] = (float)a1 * (float)a1;
    m[4] = (float)a0 * (float)a1;
  }
  #pragma unroll
  for (int j = 0; j < 5; ++j)
    #pragma unroll
    for (int off = 1; off < 64; off <<= 1) m[j] += __shfl_xor(m[j], off);
  __shared__ float sm[5][4];
  const int lane = threadIdx.x & 63, wv = threadIdx.x >> 6;
  if (lane == 0)
    #pragma unroll
    for (int j = 0; j < 5; ++j) sm[j][wv] = m[j];
  __syncthreads();
  if (threadIdx.x == 0)
    #pragma unroll
    for (int j = 0; j < 5; ++j)
      momp[j * NBC + blockIdx.x] = sm[j][0] + sm[j][1] + sm[j][2] + sm[j][3];
}

__global__ __launch_bounds__(128) void k_bnmom(const float* __restrict__ momp,
                                               const float* __restrict__ ee,
                                               const float* __restrict__ g,
                                               const float* __restrict__ b,
                                               float* __restrict__ a,
                                               float* __restrict__ c) {
  __shared__ float red[5][128];
  const int t = threadIdx.x;
  float s[5] = {0.f, 0.f, 0.f, 0.f, 0.f};
  for (int i = t; i < NBC; i += 128)
    #pragma unroll
    for (int j = 0; j < 5; ++j) s[j] += momp[j * NBC + i];
  #pragma unroll
  for (int j = 0; j < 5; ++j) red[j][t] = s[j];
  __syncthreads();
  for (int off = 64; off; off >>= 1) {
    if (t < off)
      #pragma unroll
      for (int j = 0; j < 5; ++j) red[j][t] += red[j][t + off];
    __syncthreads();
  }
  const float S0 = red[0][0], S1 = red[1][0];
  const float S00 = red[2][0], S11 = red[3][0], S01 = red[4][0];
  const float inv_n = 1.0f / (float)NN;
  const float e0 = ee[t], e1 = ee[128 + t];
  const float mean = (S0 * e0 + S1 * e1) * inv_n;
  const float msq = (S00 * e0 * e0 + 2.f * S01 * e0 * e1 + S11 * e1 * e1) * inv_n;
  float var = fmaxf(msq - mean * mean, 0.f);
  const float rs = rsqrtf(var + BN_EPS);
  const float av = g[t] * rs;
  a[t] = av;
  c[t] = b[t] - mean * av;
}

// ---------------- aggregation (fp16 reps, bit31-masked csr) ----------------
__global__ __launch_bounds__(256) void k_agg(const __half* __restrict__ h,
                                             const int* __restrict__ rp,
                                             const int* __restrict__ csr,
                                             float* __restrict__ z) {
  const int wid = blockIdx.x * 4 + (threadIdx.x >> 6);
  const int lane = threadIdx.x & 63;
  if (wid >= NN) return;
  const int beg = rp[wid], end = rp[wid + 1];
  float2 acc = __half22float2(*((const __half2*)(h + (size_t)wid * HID) + lane));
  for (int j = beg; j < end; j += 64) {
    const int cnt = min(64, end - j);
    int idx = (lane < cnt) ? (csr[j + lane] & 0x7fffffff) : 0;
    idx = min(idx, NN - 1);
    int k = 0;
    for (; k + 4 <= cnt; k += 4) {
      const int s0 = __shfl(idx, k + 0), s1 = __shfl(idx, k + 1);
      const int s2 = __shfl(idx, k + 2), s3 = __shfl(idx, k + 3);
      const float2 v0 = __half22float2(*((const __half2*)(h + (size_t)s0 * HID) + lane));
      const float2 v1 = __half22float2(*((const __half2*)(h + (size_t)s1 * HID) + lane));
      const float2 v2 = __half22float2(*((const __half2*)(h + (size_t)s2 * HID) + lane));
      const float2 v3 = __half22float2(*((const __half2*)(h + (size_t)s3 * HID) + lane));
      acc.x += (v0.x + v1.x) + (v2.x + v3.x);
      acc.y += (v0.y + v1.y) + (v2.y + v3.y);
    }
    for (; k < cnt; ++k) {
      const int s = __shfl(idx, k);
      const float2 v = __half22float2(*((const __half2*)(h + (size_t)s * HID) + lane));
      acc.x += v.x;
      acc.y += v.y;
    }
  }
  *(float2*)(z + (size_t)wid * HID + lane * 2) = acc;
}

// ---------------- barrier-free split-bf16 MFMA GEMM, wave-owns-rows ----------------
// BM2=128, 4 waves x (32 rows x 128 cols). All fragments (A and W) loaded directly
// from global (L2/L3-resident); no K-loop barriers; in-place safe (wave owns rows).
// IN_ACT: 0 identity, 1 relu(a*ina+inc), 2 rank-2 expand (a01/ee) + relu(.*ina+inc)
template <int IN_ACT>
__global__ __launch_bounds__(256, 4) void k_gemm2(
    const float* __restrict__ A, const short* __restrict__ Wsp,
    const float* __restrict__ ina, const float* __restrict__ inc,
    float* __restrict__ out, float* __restrict__ part,
    const int* __restrict__ a01, const float* __restrict__ ee) {
  __shared__ float red[4][256];
  const int tid = threadIdx.x;
  const int lane = tid & 63, wv = tid >> 6;
  const int tq = lane >> 4, tl = lane & 15;
  const int rw = blockIdx.x * BM2 + wv * 32;

  f32x4 acc[2][8];
  #pragma unroll
  for (int i = 0; i < 2; ++i)
    #pragma unroll
    for (int j = 0; j < 8; ++j) acc[i][j] = (f32x4)(0.f);

  int a01r[2] = {0, 0};
  if (IN_ACT == 2) {
    a01r[0] = a01[min(rw + tl, NN - 1)];
    a01r[1] = a01[min(rw + 16 + tl, NN - 1)];
  }

  #pragma unroll
  for (int ks = 0; ks < 4; ++ks) {
    const int kg = ks * 32 + tq * 8;
    float aa[8], cc[8];
    if (IN_ACT >= 1) {
      const float4 a0 = *(const float4*)(ina + kg);
      const float4 a1 = *(const float4*)(ina + kg + 4);
      const float4 c0 = *(const float4*)(inc + kg);
      const float4 c1 = *(const float4*)(inc + kg + 4);
      aa[0] = a0.x; aa[1] = a0.y; aa[2] = a0.z; aa[3] = a0.w;
      aa[4] = a1.x; aa[5] = a1.y; aa[6] = a1.z; aa[7] = a1.w;
      cc[0] = c0.x; cc[1] = c0.y; cc[2] = c0.z; cc[3] = c0.w;
      cc[4] = c1.x; cc[5] = c1.y; cc[6] = c1.z; cc[7] = c1.w;
    }
    float e0v[8], e1v[8];
    if (IN_ACT == 2) {
      const float4 p0 = *(const float4*)(ee + kg);
      const float4 p1 = *(const float4*)(ee + kg + 4);
      const float4 q0 = *(const float4*)(ee + 128 + kg);
      const float4 q1 = *(const float4*)(ee + 128 + kg + 4);
      e0v[0] = p0.x; e0v[1] = p0.y; e0v[2] = p0.z; e0v[3] = p0.w;
      e0v[4] = p1.x; e0v[5] = p1.y; e0v[6] = p1.z; e0v[7] = p1.w;
      e1v[0] = q0.x; e1v[1] = q0.y; e1v[2] = q0.z; e1v[3] = q0.w;
      e1v[4] = q1.x; e1v[5] = q1.y; e1v[6] = q1.z; e1v[7] = q1.w;
    }
    bf16x8 ah[2], al[2];
    #pragma unroll
    for (int fm = 0; fm < 2; ++fm) {
      const int row = rw + fm * 16 + tl;
      const int rc = min(row, NN - 1);
      float vv[8];
      if (IN_ACT == 2) {
        const float b0 = (float)(a01r[fm] & 0xffff);
        const float b1 = (float)(a01r[fm] >> 16);
        #pragma unroll
        for (int j = 0; j < 8; ++j) vv[j] = b0 * e0v[j] + b1 * e1v[j];
      } else {
        const float4 v0 = *(const float4*)(A + (size_t)rc * HID + kg);
        const float4 v1 = *(const float4*)(A + (size_t)rc * HID + kg + 4);
        vv[0] = v0.x; vv[1] = v0.y; vv[2] = v0.z; vv[3] = v0.w;
        vv[4] = v1.x; vv[5] = v1.y; vv[6] = v1.z; vv[7] = v1.w;
      }
      if (IN_ACT >= 1) {
        #pragma unroll
        for (int j = 0; j < 8; ++j) vv[j] = fmaxf(fmaf(vv[j], aa[j], cc[j]), 0.f);
      }
      if (row >= NN) {
        #pragma unroll
        for (int j = 0; j < 8; ++j) vv[j] = 0.f;
      }
      #pragma unroll
      for (int j = 0; j < 8; ++j) {
        const unsigned short hb = f2bf(vv[j]);
        ah[fm][j] = (short)hb;
        al[fm][j] = (short)f2bf(vv[j] - bf2f(hb));
      }
    }
    #pragma unroll
    for (int fn = 0; fn < 8; ++fn) {
      const int n = fn * 16 + tl;
      const bf16x8 wh = *(const bf16x8*)(Wsp + n * HID + kg);
      const bf16x8 wl = *(const bf16x8*)(Wsp + 16384 + n * HID + kg);
      #pragma unroll
      for (int fm = 0; fm < 2; ++fm) {
        acc[fm][fn] = __builtin_amdgcn_mfma_f32_16x16x32_bf16(ah[fm], wh, acc[fm][fn], 0, 0, 0);
        acc[fm][fn] = __builtin_amdgcn_mfma_f32_16x16x32_bf16(ah[fm], wl, acc[fm][fn], 0, 0, 0);
        acc[fm][fn] = __builtin_amdgcn_mfma_f32_16x16x32_bf16(al[fm], wh, acc[fm][fn], 0, 0, 0);
      }
    }
  }

  // stores: wave owns rows rw..rw+31; C/D layout col=lane&15, row=(lane>>4)*4+reg
  #pragma unroll
  for (int fm = 0; fm < 2; ++fm) {
    #pragma unroll
    for (int reg = 0; reg < 4; ++reg) {
      const int row = rw + fm * 16 + tq * 4 + reg;
      if (row < NN) {
        float* op = out + (size_t)row * HID + tl;
        #pragma unroll
        for (int fn = 0; fn < 8; ++fn) op[fn * 16] = acc[fm][fn][reg];
      }
    }
  }
  // column stats (invalid rows contributed zeros)
  float cs[8], cq[8];
  #pragma unroll
  for (int fn = 0; fn < 8; ++fn) {
    float s = 0.f, q = 0.f;
    #pragma unroll
    for (int fm = 0; fm < 2; ++fm)
      #pragma unroll
      for (int reg = 0; reg < 4; ++reg) {
        const float v = acc[fm][fn][reg];
        s += v;
        q = fmaf(v, v, q);
      }
    cs[fn] = s;
    cq[fn] = q;
  }
  #pragma unroll
  for (int fn = 0; fn < 8; ++fn) {
    cs[fn] += __shfl_xor(cs[fn], 16); cq[fn] += __shfl_xor(cq[fn], 16);
    cs[fn] += __shfl_xor(cs[fn], 32); cq[fn] += __shfl_xor(cq[fn], 32);
  }
  if (lane < 16) {
    #pragma unroll
    for (int fn = 0; fn < 8; ++fn) {
      red[wv][fn * 16 + tl] = cs[fn];
      red[wv][128 + fn * 16 + tl] = cq[fn];  // NOTE: overwrites? no — cols disjoint per fn? 128+fn*16+tl spans 128..255 ✓ and fn*16+tl spans 0..127 ✓
    }
  }
  __syncthreads();
  part[(size_t)blockIdx.x * 256 + tid] =
      red[0][tid] + red[1][tid] + red[2][tid] + red[3][tid];
}

// ---------------- barrier-free readout GEMM: fp16 hi-only, wave-owns-rows, no LDS ----
// out[n] = relu(sum_i h_i@rW1_i + (x?r1:r0) + rb1) . rW2 + rb2 ; K=384
__global__ __launch_bounds__(256, 4) void k_rdgemm2(
    const __half* __restrict__ h1, const __half* __restrict__ h2,
    const __half* __restrict__ h3, const short* __restrict__ wsp,
    const int* __restrict__ x, const float* __restrict__ ee,
    const float* __restrict__ rb1, const float* __restrict__ rW2,
    const float* __restrict__ rb2, float* __restrict__ out) {
  const int tid = threadIdx.x;
  const int lane = tid & 63, wv = tid >> 6;
  const int tq = lane >> 4, tl = lane & 15;
  const int rw = blockIdx.x * BM2 + wv * 32;

  f32x4 acc[2][8];
  #pragma unroll
  for (int i = 0; i < 2; ++i)
    #pragma unroll
    for (int j = 0; j < 8; ++j) acc[i][j] = (f32x4)(0.f);

  const int rc0 = min(rw + tl, NN - 1);
  const int rc1 = min(rw + 16 + tl, NN - 1);

  #pragma unroll
  for (int t6 = 0; t6 < 6; ++t6) {  // K=384: {h1,h2,h3} x {0,64}
    const __half* hsrc = (t6 < 2) ? h1 : (t6 < 4) ? h2 : h3;
    const short* Ws = wsp + (size_t)(t6 >> 1) * 32768;
    const int kt = (t6 & 1) * 64;
    #pragma unroll
    for (int kc = 0; kc < 2; ++kc) {
      const int kg = kt + kc * 32 + tq * 8;
      f16x8 a[2];
      a[0] = *(const f16x8*)((const _Float16*)hsrc + (size_t)rc0 * HID + kg);
      a[1] = *(const f16x8*)((const _Float16*)hsrc + (size_t)rc1 * HID + kg);
      #pragma unroll
      for (int fn = 0; fn < 8; ++fn) {
        const f16x8 wh = *(const f16x8*)(Ws + (fn * 16 + tl) * HID + kg);
        acc[0][fn] = __builtin_amdgcn_mfma_f32_16x16x32_f16(a[0], wh, acc[0][fn], 0, 0, 0);
        acc[1][fn] = __builtin_amdgcn_mfma_f32_16x16x32_f16(a[1], wh, acc[1][fn], 0, 0, 0);
      }
    }
  }

  // per-lane column constants for cols fn*16+tl
  float rbv[8], w2v[8], r0v[8], r1v[8];
  #pragma unroll
  for (int fn = 0; fn < 8; ++fn) {
    const int col = fn * 16 + tl;
    rbv[fn] = rb1[col];
    w2v[fn] = rW2[col];
    r0v[fn] = ee[256 + col];
    r1v[fn] = ee[384 + col];
  }
  const float b2 = rb2[0];
  // row-wise: relu + dot(rW2) + reduce over tl (cols) — wave-internal, no LDS
  #pragma unroll
  for (int fm = 0; fm < 2; ++fm) {
    #pragma unroll
    for (int reg = 0; reg < 4; ++reg) {
      const int row = rw + fm * 16 + tq * 4 + reg;
      const int xv = x[min(row, NN - 1)] & 1;
      float p = 0.f;
      #pragma unroll
      for (int fn = 0; fn < 8; ++fn) {
        const float g = acc[fm][fn][reg] + rbv[fn] + (xv ? r1v[fn] : r0v[fn]);
        p = fmaf(fmaxf(g, 0.f), w2v[fn], p);
      }
      p += __shfl_xor(p, 1);
      p += __shfl_xor(p, 2);
      p += __shfl_xor(p, 4);
      p += __shfl_xor(p, 8);
      if (tl == 0 && row < NN) out[row] = p + b2;
    }
  }
}

// ---------------- fused stats reduce + BN finalize ----------------
__global__ __launch_bounds__(256) void k_bnstat(const float* __restrict__ part,
                                                const float* __restrict__ g,
                                                const float* __restrict__ b,
                                                float* __restrict__ a,
                                                float* __restrict__ c,
                                                float* __restrict__ S,
                                                int* __restrict__ ctr) {
  const int tid = threadIdx.x;
  float acc = 0.f;
  for (int r = blockIdx.x; r < NBLK2; r += 64) acc += part[(size_t)r * 256 + tid];
  atomicAdd(&S[tid], acc);
  __syncthreads();
  __threadfence();
  __shared__ int last;
  if (tid == 0) last = (atomicAdd(ctr, 1) == 63);
  __syncthreads();
  if (!last) return;
  __threadfence();
  const float tot = atomicAdd(&S[tid], 0.f);
  __shared__ float sm[256];
  sm[tid] = tot;
  __syncthreads();
  if (tid < 128) {
    const float inv_n = 1.0f / (float)NN;
    const float mean = sm[tid] * inv_n;
    float var = fmaxf(sm[tid + 128] * inv_n - mean * mean, 0.f);
    const float rs = rsqrtf(var + BN_EPS);
    const float av = g[tid] * rs;
    a[tid] = av;
    c[tid] = b[tid] - mean * av;
  }
}

// ---------------- elementwise: h = elu(v*a + c) -> fp16 ----------------
__global__ __launch_bounds__(256) void k_act(const float* __restrict__ v,
                                             const float* __restrict__ a,
                                             const float* __restrict__ c,
                                             __half* __restrict__ h) {
  const int total = NN * 32;
  for (int i = blockIdx.x * blockDim.x + threadIdx.x; i < total;
       i += gridDim.x * blockDim.x) {
    const int node = i >> 5, q = i & 31;
    const float4 vv = *(const float4*)(v + (size_t)node * HID + q * 4);
    const float4 a4 = ((const float4*)a)[q];
    const float4 c4 = ((const float4*)c)[q];
    float z;
    float o0, o1, o2, o3;
    z = fmaf(vv.x, a4.x, c4.x); o0 = z > 0.f ? z : expm1f(z);
    z = fmaf(vv.y, a4.y, c4.y); o1 = z > 0.f ? z : expm1f(z);
    z = fmaf(vv.z, a4.z, c4.z); o2 = z > 0.f ? z : expm1f(z);
    z = fmaf(vv.w, a4.w, c4.w); o3 = z > 0.f ? z : expm1f(z);
    const __half2 p0 = __floats2half2_rn(o0, o1);
    const __half2 p1 = __floats2half2_rn(o2, o3);
    uint2 u;
    u.x = *reinterpret_cast<const unsigned*>(&p0);
    u.y = *reinterpret_cast<const unsigned*>(&p1);
    *(uint2*)(h + (size_t)node * HID + q * 4) = u;
  }
}

// ---------------- launcher ----------------
extern "C" void kernel_launch(void* const* d_in, const int* in_sizes, int n_in,
                              void* d_out, int out_size, void* d_ws,
                              size_t ws_size, hipStream_t stream) {
  if (ws_size < WS_NEEDED) return;

  const int* x = (const int*)d_in[0];
  const int* E = (const int*)d_in[1];
  const float* emb = (const float*)d_in[2];
  const float* W1 = (const float*)d_in[3];
  const float* W2 = (const float*)d_in[4];
  const float* bn1g = (const float*)d_in[5];
  const float* bn1b = (const float*)d_in[6];
  const float* bn2g = (const float*)d_in[7];
  const float* bn2b = (const float*)d_in[8];
  const float* rW1 = (const float*)d_in[9];
  const float* rb1 = (const float*)d_in[10];
  const float* rW2 = (const float*)d_in[11];
  const float* rb2 = (const float*)d_in[12];
  float* outp = (float*)d_out;

  char* ws = (char*)d_ws;
  float* P = (float*)(ws + OFF_P);
  float* Q = (float*)(ws + OFF_Q);
  float* R = (float*)(ws + OFF_R);
  int* csr = (int*)(ws + OFF_CSR);
  int* rp = (int*)(ws + OFF_RP);
  int* cnt = (int*)(ws + OFF_CNT);
  int* bs = (int*)(ws + OFF_BS);
  int* flag = (int*)(ws + OFF_FLG);
  float* SS = (float*)(ws + OFF_SS);
  int* SCT = (int*)(ws + OFF_SCT);
  float* ac = (float*)(ws + OFF_AC);
  float* ee = (float*)(ws + OFF_E);
  short* wsp = (short*)(ws + OFF_WSP);
  __half* h1 = (__half*)P;
  __half* h2 = (__half*)((char*)P + SZ_H16);
  __half* h3 = (__half*)R;
  float* part = R;                 // 0.8 MB, time-shared with h3
  int* a01 = (int*)((char*)P + (4 << 20));
  float* momp = (float*)((char*)P + (8 << 20));

  hipMemsetAsync(ws + OFF_ZZ, 0, ZZ_BYTES, stream);
  k_detect<<<1, 64, 0, stream>>>(E, flag);
  k_hist<<<SC_CHUNKS * 8, 256, 0, stream>>>(E, flag, cnt);
  k_scan1<<<NB_SCAN, 256, 0, stream>>>(cnt, rp, bs);
  k_scan2<<<1, 128, 0, stream>>>(bs);
  k_scan3<<<NB_SCAN, 256, 0, stream>>>(rp, bs, cnt);
  k_scatter<<<SC_CHUNKS * 8, 256, 0, stream>>>(E, flag, x, cnt, csr);
  k_prep<<<1, 256, 0, stream>>>(emb, W1, rW1, ee);
  k_prepw<<<512, 256, 0, stream>>>(W1, W2, rW1, wsp);

  float* a1 = ac + 0 * 256, *c1 = a1 + HID;
  float* a2 = ac + 1 * 256, *c2 = a2 + HID;

  // ---- layer 1 (rank-2 shortcut; u1 expanded inside the GEMM) ----
  k_cnt<<<NBC, 256, 0, stream>>>(x, rp, csr, a01, momp);
  k_bnmom<<<1, 128, 0, stream>>>(momp, ee, bn1g, bn1b, a1, c1);
  k_gemm2<2><<<NBLK2, 256, 0, stream>>>(Q, wsp + 0 * 32768, a1, c1, Q, part,
                                        a01, ee);
  k_bnstat<<<64, 256, 0, stream>>>(part, bn2g, bn2b, a2, c2, SS + 0 * 256, SCT + 0);
  k_act<<<2048, 256, 0, stream>>>(Q, a2, c2, h1);

  // ---- layers 2,3 ----
  int inst = 1;
  for (int i = 1; i < 3; ++i) {
    float* b1a = ac + (2 * i) * 256, *b1c = b1a + HID;
    float* b2a = ac + (2 * i + 1) * 256, *b2c = b2a + HID;
    const int s1 = (i == 1) ? 1 : 3;  // W1[i] slot
    const __half* hin = (i == 1) ? h1 : h2;
    k_agg<<<NN / 4, 256, 0, stream>>>(hin, rp, csr, Q);
    k_gemm2<0><<<NBLK2, 256, 0, stream>>>(Q, wsp + (size_t)s1 * 32768, nullptr,
                                          nullptr, Q, part, nullptr, nullptr);
    k_bnstat<<<64, 256, 0, stream>>>(part, bn1g + i * HID, bn1b + i * HID, b1a,
                                     b1c, SS + inst * 256, SCT + inst);
    ++inst;
    k_gemm2<1><<<NBLK2, 256, 0, stream>>>(Q, wsp + (size_t)(s1 + 1) * 32768,
                                          b1a, b1c, Q, part, nullptr, nullptr);
    k_bnstat<<<64, 256, 0, stream>>>(part, bn2g + i * HID, bn2b + i * HID, b2a,
                                     b2c, SS + inst * 256, SCT + inst);
    ++inst;
    k_act<<<2048, 256, 0, stream>>>(Q, b2a, b2c, (i == 1) ? h2 : h3);
  }

  // ---- fused readout GEMM over [h1|h2|h3] + rank-2 rep0 bias ----
  k_rdgemm2<<<NBLK2, 256, 0, stream>>>(h1, h2, h3, wsp + (size_t)5 * 32768, x,
                                       ee, rb1, rW2, rb2, outp);
}

// Round 11
// 684.193 us; speedup vs baseline: 1.1972x; 1.1972x over previous
//
#include <hip/hip_runtime.h>
#include <hip/hip_fp16.h>
#include <cstdint>
#include <cstddef>

#define NN 100000
#define NE 1600000
#define HID 128
#define BN_EPS 1e-5f
#define NB_SCAN 98  // ceil(100000/1024)
#define BM 96
#define NBLK ((NN + BM - 1) / BM)   // 1042 gemm blocks
#define NBC  ((NN + 255) / 256)     // 391 count blocks
#define SA 72   // LDS stride (16-bit elems)
#define SC_CHUNKS 256
#define SC_RANGE (NN / 8)           // 12500
#define SC_EPC (NE / SC_CHUNKS)     // 6250

typedef __attribute__((ext_vector_type(8))) short bf16x8;
typedef __attribute__((ext_vector_type(8))) _Float16 f16x8;
typedef __attribute__((ext_vector_type(4))) float f32x4;
typedef __attribute__((ext_vector_type(4))) unsigned short u16x4;

// ---------------- workspace layout (bytes) ----------------
static constexpr size_t SZ_NODE = (size_t)NN * HID * 4;            // 51.2 MB
static constexpr size_t SZ_H16  = (size_t)NN * HID * 2;            // 25.6 MB
static constexpr size_t OFF_P   = 0;                               // h1 fp16 + h2 fp16
static constexpr size_t OFF_Q   = SZ_NODE;                         // z/u/v in-place chain (fp32)
static constexpr size_t OFF_R   = 2 * SZ_NODE;                     // part (1.07MB) then h3 fp16
static constexpr size_t OFF_CSR = 3 * SZ_NODE;
static constexpr size_t OFF_RP  = OFF_CSR + (size_t)NE * 4;
static constexpr size_t OFF_ZZ  = ((OFF_RP + (size_t)(NN + 1) * 4 + 255) / 256) * 256;
static constexpr size_t OFF_CNT = OFF_ZZ;
static constexpr size_t OFF_BS  = OFF_CNT + (((size_t)NN * 4 + 255) / 256) * 256;
static constexpr size_t OFF_FLG = OFF_BS + 512;
static constexpr size_t OFF_SS  = OFF_FLG + 256;                   // 5 x 256 f32 atomic sums
static constexpr size_t OFF_SCT = OFF_SS + 5 * 256 * 4;            // 5 int counters
static constexpr size_t ZZ_END  = ((OFF_SCT + 5 * 4 + 255) / 256) * 256;
static constexpr size_t ZZ_BYTES = ZZ_END - OFF_ZZ;
static constexpr size_t OFF_AC  = ZZ_END;                          // 6 x 256 f32 (bn a/c)
static constexpr size_t OFF_E   = OFF_AC + 6 * 256 * 4;            // ee: e0,e1,r0,r1 = 512 f32
static constexpr size_t OFF_WSP = OFF_E + 512 * 4;                 // 8 mats x [2][128][128] shorts
static constexpr size_t WS_NEEDED = OFF_WSP + (size_t)8 * 2 * HID * HID * 2;

// ---------------- helpers ----------------
__device__ __forceinline__ unsigned short f2bf(float f) {
  unsigned u = __float_as_uint(f);
  unsigned r = (u + 0x7fffu + ((u >> 16) & 1u)) >> 16;
  return (unsigned short)r;
}
__device__ __forceinline__ float bf2f(unsigned short b) {
  return __uint_as_float(((unsigned)b) << 16);
}
__device__ __forceinline__ int edge_at(const int* __restrict__ E, int f, int idx) {
  return f ? E[2 * (long long)idx] : E[idx];
}

// ---------------- dtype detection ----------------
__global__ void k_detect(const int* __restrict__ E, int* __restrict__ flag) {
  if (threadIdx.x == 0 && blockIdx.x == 0) {
    int f = 1;
    for (int i = 1; i < 256; i += 2)
      if (E[i] != 0) { f = 0; break; }
    *flag = f;
  }
}

// ---------------- CSR build (XCD-bucketed hist + scatter: round 6/8 verified) --------
__global__ __launch_bounds__(256) void k_hist(const int* __restrict__ E,
                                              const int* __restrict__ flag,
                                              int* __restrict__ cnt) {
  const int f = *flag;
  const int r = blockIdx.x & 7;
  const int chunk = blockIdx.x >> 3;
  const int lo = r * SC_RANGE, hi = lo + SC_RANGE;
  const int ebeg = chunk * SC_EPC, eend = ebeg + SC_EPC;
  for (int e = ebeg + threadIdx.x; e < eend; e += 256) {
    int d = edge_at(E, f, NE + e);
    d = min(max(d, 0), NN - 1);
    if (d >= lo && d < hi) atomicAdd(&cnt[d], 1);
  }
}

__global__ __launch_bounds__(256) void k_scan1(const int* __restrict__ cnt,
                                               int* __restrict__ rp,
                                               int* __restrict__ bs) {
  __shared__ int s[256];
  const int tid = threadIdx.x;
  const int base = blockIdx.x * 1024 + tid * 4;
  int v0 = 0, v1 = 0, v2 = 0, v3 = 0;
  if (base + 0 < NN) v0 = cnt[base + 0];
  if (base + 1 < NN) v1 = cnt[base + 1];
  if (base + 2 < NN) v2 = cnt[base + 2];
  if (base + 3 < NN) v3 = cnt[base + 3];
  const int t0 = v0, t1 = t0 + v1, t2 = t1 + v2, t3 = t2 + v3;
  s[tid] = t3;
  __syncthreads();
  for (int off = 1; off < 256; off <<= 1) {
    int xv = 0;
    if (tid >= off) xv = s[tid - off];
    __syncthreads();
    if (tid >= off) s[tid] += xv;
    __syncthreads();
  }
  const int excl = tid ? s[tid - 1] : 0;
  if (base + 0 < NN) rp[base + 0] = excl;
  if (base + 1 < NN) rp[base + 1] = excl + t0;
  if (base + 2 < NN) rp[base + 2] = excl + t1;
  if (base + 3 < NN) rp[base + 3] = excl + t2;
  if (tid == 255) bs[blockIdx.x] = s[255];
}

__global__ __launch_bounds__(128) void k_scan2(int* __restrict__ bs) {
  __shared__ int s[128];
  const int tid = threadIdx.x;
  s[tid] = (tid < NB_SCAN) ? bs[tid] : 0;
  __syncthreads();
  for (int off = 1; off < 128; off <<= 1) {
    int xv = 0;
    if (tid >= off) xv = s[tid - off];
    __syncthreads();
    if (tid >= off) s[tid] += xv;
    __syncthreads();
  }
  if (tid < NB_SCAN) bs[tid] = tid ? s[tid - 1] : 0;
}

__global__ __launch_bounds__(256) void k_scan3(int* __restrict__ rp,
                                               const int* __restrict__ bs,
                                               int* __restrict__ cursor) {
  const int off = bs[blockIdx.x];
  const int base = blockIdx.x * 1024 + threadIdx.x * 4;
  #pragma unroll
  for (int j = 0; j < 4; ++j) {
    const int i = base + j;
    if (i < NN) {
      const int v = rp[i] + off;
      rp[i] = v;
      cursor[i] = v;
    }
  }
  if (blockIdx.x == 0 && threadIdx.x == 0) rp[NN] = NE;
}

// scatter embeds x[src] in csr bit31: downstream k_cnt reads csr LINEARLY
__global__ __launch_bounds__(256) void k_scatter(const int* __restrict__ E,
                                                 const int* __restrict__ flag,
                                                 const int* __restrict__ x,
                                                 int* __restrict__ cursor,
                                                 int* __restrict__ csr) {
  const int f = *flag;
  const int r = blockIdx.x & 7;
  const int chunk = blockIdx.x >> 3;
  const int lo = r * SC_RANGE, hi = lo + SC_RANGE;
  const int ebeg = chunk * SC_EPC, eend = ebeg + SC_EPC;
  for (int e = ebeg + threadIdx.x; e < eend; e += 256) {
    int d = edge_at(E, f, NE + e);
    d = min(max(d, 0), NN - 1);
    if (d >= lo && d < hi) {
      int s = edge_at(E, f, e);
      s = min(max(s, 0), NN - 1);
      const int xb = x[s] & 1;            // 400KB table: L2-resident gather
      const int pos = atomicAdd(&cursor[d], 1);
      if ((unsigned)pos < (unsigned)NE) csr[pos] = s | (xb << 31);
    }
  }
}

// ---------------- weight pre-split ----------------
// slots 0-4 (layer GEMMs, bf16 hi/lo): 0=W2[0] 1=W1[1] 2=W2[1] 3=W1[2] 4=W2[2]
// slots 5-7 (rdgemm, fp16 hi only): 5=rW1[1] 6=rW1[2] 7=rW1[3]
__global__ __launch_bounds__(256) void k_prepw(const float* __restrict__ W1,
                                               const float* __restrict__ W2,
                                               const float* __restrict__ rW1,
                                               short* __restrict__ wsp) {
  const int g = blockIdx.x * 256 + threadIdx.x;
  const int m = g >> 14, idx = g & 16383;
  const int k = idx >> 7, n = idx & 127;
  const float* src;
  switch (m) {
    case 0: src = W2; break;
    case 1: src = W1 + 1 * HID * HID; break;
    case 2: src = W2 + 1 * HID * HID; break;
    case 3: src = W1 + 2 * HID * HID; break;
    case 4: src = W2 + 2 * HID * HID; break;
    case 5: src = rW1 + 1 * HID * HID; break;
    case 6: src = rW1 + 2 * HID * HID; break;
    default: src = rW1 + 3 * HID * HID; break;
  }
  const float v = src[k * HID + n];
  short* dst = wsp + (size_t)m * 32768;
  if (m < 5) {
    const unsigned short hb = f2bf(v);
    dst[n * HID + k] = (short)hb;
    dst[16384 + n * HID + k] = (short)f2bf(v - bf2f(hb));
  } else {
    const __half hh = __float2half_rn(v);
    dst[n * HID + k] = (short)__half_as_ushort(hh);
    dst[16384 + n * HID + k] = 0;
  }
}

// ---------------- layer-1 rank-2 shortcut ----------------
__global__ __launch_bounds__(256) void k_prep(const float* __restrict__ emb,
                                              const float* __restrict__ W1,
                                              const float* __restrict__ rW1,
                                              float* __restrict__ ee) {
  const int t = threadIdx.x;
  const int f = t & 127;
  const float* er = emb + (t >> 7) * HID;
  float se = 0.f, sr = 0.f;
  for (int k = 0; k < HID; ++k) {
    const float ev = er[k];
    se = fmaf(ev, W1[k * HID + f], se);
    sr = fmaf(ev, rW1[k * HID + f], sr);
  }
  ee[t] = se;        // e0,e1
  ee[256 + t] = sr;  // r0,r1
}

// per-node class counts from LINEAR csr read (x-bit in bit31)
__global__ __launch_bounds__(256) void k_cnt(const int* __restrict__ x,
                                             const int* __restrict__ rp,
                                             const int* __restrict__ csr,
                                             int* __restrict__ a01,
                                             float* __restrict__ momp) {
  const int n = blockIdx.x * 256 + threadIdx.x;
  float m[5] = {0.f, 0.f, 0.f, 0.f, 0.f};
  if (n < NN) {
    const int beg = rp[n], end = rp[n + 1];
    int c1 = 0;
    for (int j = beg; j < end; ++j) c1 += (int)(((unsigned)csr[j]) >> 31);
    const int a1 = c1 + (x[n] & 1);
    const int a0 = (end - beg + 1) - a1;
    a01[n] = a0 | (a1 << 16);
    m[0] = (float)a0;
    m[1] = (float)a1;
    m[2] = (float)a0 * (float)a0;
    m[3] = (float)a1 * (float)a1;
    m[4] = (float)a0 * (float)a1;
  }
  #pragma unroll
  for (int j = 0; j < 5; ++j)
    #pragma unroll
    for (int off = 1; off < 64; off <<= 1) m[j] += __shfl_xor(m[j], off);
  __shared__ float sm[5][4];
  const int lane = threadIdx.x & 63, wv = threadIdx.x >> 6;
  if (lane == 0)
    #pragma unroll
    for (int j = 0; j < 5; ++j) sm[j][wv] = m[j];
  __syncthreads();
  if (threadIdx.x == 0)
    #pragma unroll
    for (int j = 0; j < 5; ++j)
      momp[j * NBC + blockIdx.x] = sm[j][0] + sm[j][1] + sm[j][2] + sm[j][3];
}

__global__ __launch_bounds__(128) void k_bnmom(const float* __restrict__ momp,
                                               const float* __restrict__ ee,
                                               const float* __restrict__ g,
                                               const float* __restrict__ b,
                                               float* __restrict__ a,
                                               float* __restrict__ c) {
  __shared__ float red[5][128];
  const int t = threadIdx.x;
  float s[5] = {0.f, 0.f, 0.f, 0.f, 0.f};
  for (int i = t; i < NBC; i += 128)
    #pragma unroll
    for (int j = 0; j < 5; ++j) s[j] += momp[j * NBC + i];
  #pragma unroll
  for (int j = 0; j < 5; ++j) red[j][t] = s[j];
  __syncthreads();
  for (int off = 64; off; off >>= 1) {
    if (t < off)
      #pragma unroll
      for (int j = 0; j < 5; ++j) red[j][t] += red[j][t + off];
    __syncthreads();
  }
  const float S0 = red[0][0], S1 = red[1][0];
  const float S00 = red[2][0], S11 = red[3][0], S01 = red[4][0];
  const float inv_n = 1.0f / (float)NN;
  const float e0 = ee[t], e1 = ee[128 + t];
  const float mean = (S0 * e0 + S1 * e1) * inv_n;
  const float msq = (S00 * e0 * e0 + 2.f * S01 * e0 * e1 + S11 * e1 * e1) * inv_n;
  float var = fmaxf(msq - mean * mean, 0.f);
  const float rs = rsqrtf(var + BN_EPS);
  const float av = g[t] * rs;
  a[t] = av;
  c[t] = b[t] - mean * av;
}

// ---------------- aggregation (fp16 reps, bit31-masked csr) ----------------
__global__ __launch_bounds__(256) void k_agg(const __half* __restrict__ h,
                                             const int* __restrict__ rp,
                                             const int* __restrict__ csr,
                                             float* __restrict__ z) {
  const int wid = blockIdx.x * 4 + (threadIdx.x >> 6);
  const int lane = threadIdx.x & 63;
  if (wid >= NN) return;
  const int beg = rp[wid], end = rp[wid + 1];
  float2 acc = __half22float2(*((const __half2*)(h + (size_t)wid * HID) + lane));
  for (int j = beg; j < end; j += 64) {
    const int cnt = min(64, end - j);
    int idx = (lane < cnt) ? (csr[j + lane] & 0x7fffffff) : 0;
    idx = min(idx, NN - 1);
    int k = 0;
    for (; k + 4 <= cnt; k += 4) {
      const int s0 = __shfl(idx, k + 0), s1 = __shfl(idx, k + 1);
      const int s2 = __shfl(idx, k + 2), s3 = __shfl(idx, k + 3);
      const float2 v0 = __half22float2(*((const __half2*)(h + (size_t)s0 * HID) + lane));
      const float2 v1 = __half22float2(*((const __half2*)(h + (size_t)s1 * HID) + lane));
      const float2 v2 = __half22float2(*((const __half2*)(h + (size_t)s2 * HID) + lane));
      const float2 v3 = __half22float2(*((const __half2*)(h + (size_t)s3 * HID) + lane));
      acc.x += (v0.x + v1.x) + (v2.x + v3.x);
      acc.y += (v0.y + v1.y) + (v2.y + v3.y);
    }
    for (; k < cnt; ++k) {
      const int s = __shfl(idx, k);
      const float2 v = __half22float2(*((const __half2*)(h + (size_t)s * HID) + lane));
      acc.x += v.x;
      acc.y += v.y;
    }
  }
  *(float2*)(z + (size_t)wid * HID + lane * 2) = acc;
}

// ---------------- split-bf16 MFMA GEMM, W fragments DIRECT from global ----------------
// IN_ACT: 0 identity, 1 relu(a*ina+inc), 2 rank-2 expand (a01/ee) + relu(.*ina+inc)
// OUT_MODE: 0 store + per-block column stats
template <int IN_ACT, int OUT_MODE>
__global__ __launch_bounds__(256, 4) void k_gemm(
    float* A, const short* __restrict__ Wsp,
    const float* __restrict__ ina, const float* __restrict__ inc,
    float* __restrict__ out, float* __restrict__ part,
    const int* __restrict__ a01, const float* __restrict__ ee) {
  __shared__ short Ah[BM * SA];
  __shared__ short Al[BM * SA];
  const int tid = threadIdx.x;
  const int lane = tid & 63, wv = tid >> 6;
  const int tq = lane >> 4, tl = lane & 15;
  const int wc = wv * 32;
  const int m0 = blockIdx.x * BM;

  f32x4 acc[6][2];
  #pragma unroll
  for (int i = 0; i < 6; ++i)
    #pragma unroll
    for (int j = 0; j < 2; ++j) acc[i][j] = (f32x4)(0.f);

  for (int kt = 0; kt < HID; kt += 64) {
    if (kt) __syncthreads();
    #pragma unroll
    for (int p = 0; p < 6; ++p) {
      const int flat = p * 256 + tid;
      const int m = flat >> 4, kq = flat & 15;
      const int gm = m0 + m, gk = kt + kq * 4;
      float vv[4] = {0.f, 0.f, 0.f, 0.f};
      if (gm < NN) {
        if (IN_ACT == 2) {
          const int pk = a01[gm];
          const float a0 = (float)(pk & 0xffff), a1 = (float)(pk >> 16);
          const float4 e0q = *(const float4*)(ee + gk);
          const float4 e1q = *(const float4*)(ee + 128 + gk);
          vv[0] = a0 * e0q.x + a1 * e1q.x;
          vv[1] = a0 * e0q.y + a1 * e1q.y;
          vv[2] = a0 * e0q.z + a1 * e1q.z;
          vv[3] = a0 * e0q.w + a1 * e1q.w;
        } else {
          const float4 v = *(const float4*)(A + (size_t)gm * HID + gk);
          vv[0] = v.x; vv[1] = v.y; vv[2] = v.z; vv[3] = v.w;
        }
        if (IN_ACT >= 1) {
          const float4 a4 = *(const float4*)(ina + gk);
          const float4 c4 = *(const float4*)(inc + gk);
          vv[0] = fmaxf(fmaf(vv[0], a4.x, c4.x), 0.f);
          vv[1] = fmaxf(fmaf(vv[1], a4.y, c4.y), 0.f);
          vv[2] = fmaxf(fmaf(vv[2], a4.z, c4.z), 0.f);
          vv[3] = fmaxf(fmaf(vv[3], a4.w, c4.w), 0.f);
        }
      }
      u16x4 hh, ll;
      #pragma unroll
      for (int j = 0; j < 4; ++j) {
        const unsigned short hb = f2bf(vv[j]);
        hh[j] = hb;
        ll[j] = f2bf(vv[j] - bf2f(hb));
      }
      *(u16x4*)(&Ah[m * SA + kq * 4]) = hh;
      *(u16x4*)(&Al[m * SA + kq * 4]) = ll;
    }
    __syncthreads();
    #pragma unroll
    for (int kc = 0; kc < 64; kc += 32) {
      const int lo = kc + tq * 8;
      const int go = kt + lo;
      bf16x8 wh[2], wl[2];
      #pragma unroll
      for (int fn = 0; fn < 2; ++fn) {
        const int n = wc + fn * 16 + tl;
        wh[fn] = *(const bf16x8*)(Wsp + n * HID + go);
        wl[fn] = *(const bf16x8*)(Wsp + 16384 + n * HID + go);
      }
      #pragma unroll
      for (int fm = 0; fm < 6; ++fm) {
        const int r = (fm * 16 + tl) * SA + lo;
        const bf16x8 ah = *(const bf16x8*)(&Ah[r]);
        const bf16x8 al = *(const bf16x8*)(&Al[r]);
        #pragma unroll
        for (int fn = 0; fn < 2; ++fn) {
          acc[fm][fn] = __builtin_amdgcn_mfma_f32_16x16x32_bf16(ah, wh[fn], acc[fm][fn], 0, 0, 0);
          acc[fm][fn] = __builtin_amdgcn_mfma_f32_16x16x32_bf16(ah, wl[fn], acc[fm][fn], 0, 0, 0);
          acc[fm][fn] = __builtin_amdgcn_mfma_f32_16x16x32_bf16(al, wh[fn], acc[fm][fn], 0, 0, 0);
        }
      }
    }
  }

  #pragma unroll
  for (int fm = 0; fm < 6; ++fm) {
    #pragma unroll
    for (int reg = 0; reg < 4; ++reg) {
      const int row = m0 + fm * 16 + tq * 4 + reg;
      if (row < NN) {
        float* op = out + (size_t)row * HID + wc + tl;
        op[0] = acc[fm][0][reg];
        op[16] = acc[fm][1][reg];
      }
    }
  }
  if (OUT_MODE == 0) {
    #pragma unroll
    for (int fn = 0; fn < 2; ++fn) {
      float s = 0.f, q = 0.f;
      #pragma unroll
      for (int fm = 0; fm < 6; ++fm)
        #pragma unroll
        for (int reg = 0; reg < 4; ++reg) {
          const float v = acc[fm][fn][reg];
          s += v;
          q = fmaf(v, v, q);
        }
      s += __shfl_xor(s, 16); q += __shfl_xor(q, 16);
      s += __shfl_xor(s, 32); q += __shfl_xor(q, 32);
      if (lane < 16) {
        const int col = wc + fn * 16 + lane;
        part[(size_t)blockIdx.x * 256 + col] = s;
        part[(size_t)blockIdx.x * 256 + 128 + col] = q;
      }
    }
  }
}

// ---------------- readout GEMM: exact-fp16 A (raw LDS copy), fp16 hi-only W ----------
// Single accumulator set (48 AGPR) -> 4 waves/SIMD; 144 MFMAs/block.
__global__ __launch_bounds__(256, 4) void k_rdgemm(
    const __half* __restrict__ h1, const __half* __restrict__ h2,
    const __half* __restrict__ h3, const short* __restrict__ wsp,
    const int* __restrict__ x, const float* __restrict__ ee,
    const float* __restrict__ rb1, const float* __restrict__ rW2,
    const float* __restrict__ rb2, float* __restrict__ out) {
  __shared__ short Ah[BM * SA];   // raw fp16
  const int tid = threadIdx.x;
  const int lane = tid & 63, wv = tid >> 6;
  const int tq = lane >> 4, tl = lane & 15;
  const int wc = wv * 32;
  const int m0 = blockIdx.x * BM;

  f32x4 acc[6][2];
  #pragma unroll
  for (int i = 0; i < 6; ++i)
    #pragma unroll
    for (int j = 0; j < 2; ++j) acc[i][j] = (f32x4)(0.f);

  for (int t6 = 0; t6 < 6; ++t6) {  // K=384: {h1,h2,h3} x {0,64}
    const __half* hsrc = (t6 < 2) ? h1 : (t6 < 4) ? h2 : h3;
    const short* Ws = wsp + (size_t)(t6 >> 1) * 32768;
    const int kt = (t6 & 1) * 64;
    if (t6) __syncthreads();
    // raw fp16 copy into LDS — zero conversion
    #pragma unroll
    for (int p = 0; p < 6; ++p) {
      const int flat = p * 256 + tid;
      const int m = flat >> 4, kq = flat & 15;
      const int gm = m0 + m, gk = kt + kq * 4;
      u16x4 hv = (u16x4)(0);
      if (gm < NN) hv = *(const u16x4*)((const unsigned short*)hsrc + (size_t)gm * HID + gk);
      *(u16x4*)(&Ah[m * SA + kq * 4]) = hv;
    }
    __syncthreads();
    #pragma unroll
    for (int kc = 0; kc < 64; kc += 32) {
      const int lo = kc + tq * 8;
      const int go = kt + lo;
      f16x8 wh[2];
      #pragma unroll
      for (int fn = 0; fn < 2; ++fn) {
        const int n = wc + fn * 16 + tl;
        wh[fn] = *(const f16x8*)(Ws + n * HID + go);
      }
      #pragma unroll
      for (int fm = 0; fm < 6; ++fm) {
        const f16x8 a = *(const f16x8*)(&Ah[(fm * 16 + tl) * SA + lo]);
        #pragma unroll
        for (int fn = 0; fn < 2; ++fn)
          acc[fm][fn] = __builtin_amdgcn_mfma_f32_16x16x32_f16(a, wh[fn], acc[fm][fn], 0, 0, 0);
      }
    }
  }

  // epilogue: + rb1 + (x ? r1 : r0), relu, dot rW2, reduce 128 cols per row
  const int c0 = wc + tl, c1 = wc + 16 + tl;
  const float rb_0 = rb1[c0], rb_1 = rb1[c1];
  const float w2_0 = rW2[c0], w2_1 = rW2[c1];
  const float r0_0 = ee[256 + c0], r0_1 = ee[256 + c1];
  const float r1_0 = ee[384 + c0], r1_1 = ee[384 + c1];
  __syncthreads();                 // done reading Ah -> reuse as reduction buffer
  float* rs = (float*)Ah;          // [96][4]
  #pragma unroll
  for (int fm = 0; fm < 6; ++fm) {
    #pragma unroll
    for (int reg = 0; reg < 4; ++reg) {
      const int row = fm * 16 + tq * 4 + reg;
      const int grow = m0 + row;
      const int xv = (grow < NN) ? (x[grow] & 1) : 0;
      const float g0 = acc[fm][0][reg] + rb_0 + (xv ? r1_0 : r0_0);
      const float g1 = acc[fm][1][reg] + rb_1 + (xv ? r1_1 : r0_1);
      float p = fmaxf(g0, 0.f) * w2_0 + fmaxf(g1, 0.f) * w2_1;
      p += __shfl_xor(p, 1);
      p += __shfl_xor(p, 2);
      p += __shfl_xor(p, 4);
      p += __shfl_xor(p, 8);
      if (tl == 0) rs[row * 4 + wv] = p;
    }
  }
  __syncthreads();
  if (tid < BM) {
    const int grow = m0 + tid;
    if (grow < NN)
      out[grow] = rs[tid * 4 + 0] + rs[tid * 4 + 1] + rs[tid * 4 + 2] +
                  rs[tid * 4 + 3] + rb2[0];
  }
}

// ---------------- fused stats reduce + BN finalize ----------------
__global__ __launch_bounds__(256) void k_bnstat(const float* __restrict__ part,
                                                const float* __restrict__ g,
                                                const float* __restrict__ b,
                                                float* __restrict__ a,
                                                float* __restrict__ c,
                                                float* __restrict__ S,
                                                int* __restrict__ ctr) {
  const int tid = threadIdx.x;
  float acc = 0.f;
  for (int r = blockIdx.x; r < NBLK; r += 64) acc += part[(size_t)r * 256 + tid];
  atomicAdd(&S[tid], acc);
  __syncthreads();
  __threadfence();
  __shared__ int last;
  if (tid == 0) last = (atomicAdd(ctr, 1) == 63);
  __syncthreads();
  if (!last) return;
  __threadfence();
  const float tot = atomicAdd(&S[tid], 0.f);
  __shared__ float sm[256];
  sm[tid] = tot;
  __syncthreads();
  if (tid < 128) {
    const float inv_n = 1.0f / (float)NN;
    const float mean = sm[tid] * inv_n;
    float var = fmaxf(sm[tid + 128] * inv_n - mean * mean, 0.f);
    const float rs = rsqrtf(var + BN_EPS);
    const float av = g[tid] * rs;
    a[tid] = av;
    c[tid] = b[tid] - mean * av;
  }
}

// ---------------- elementwise: h = elu(v*a + c) -> fp16 ----------------
__global__ __launch_bounds__(256) void k_act(const float* __restrict__ v,
                                             const float* __restrict__ a,
                                             const float* __restrict__ c,
                                             __half* __restrict__ h) {
  const int total = NN * 32;
  for (int i = blockIdx.x * blockDim.x + threadIdx.x; i < total;
       i += gridDim.x * blockDim.x) {
    const int node = i >> 5, q = i & 31;
    const float4 vv = *(const float4*)(v + (size_t)node * HID + q * 4);
    const float4 a4 = ((const float4*)a)[q];
    const float4 c4 = ((const float4*)c)[q];
    float z;
    float o0, o1, o2, o3;
    z = fmaf(vv.x, a4.x, c4.x); o0 = z > 0.f ? z : expm1f(z);
    z = fmaf(vv.y, a4.y, c4.y); o1 = z > 0.f ? z : expm1f(z);
    z = fmaf(vv.z, a4.z, c4.z); o2 = z > 0.f ? z : expm1f(z);
    z = fmaf(vv.w, a4.w, c4.w); o3 = z > 0.f ? z : expm1f(z);
    const __half2 p0 = __floats2half2_rn(o0, o1);
    const __half2 p1 = __floats2half2_rn(o2, o3);
    uint2 u;
    u.x = *reinterpret_cast<const unsigned*>(&p0);
    u.y = *reinterpret_cast<const unsigned*>(&p1);
    *(uint2*)(h + (size_t)node * HID + q * 4) = u;
  }
}

// ---------------- launcher ----------------
extern "C" void kernel_launch(void* const* d_in, const int* in_sizes, int n_in,
                              void* d_out, int out_size, void* d_ws,
                              size_t ws_size, hipStream_t stream) {
  if (ws_size < WS_NEEDED) return;

  const int* x = (const int*)d_in[0];
  const int* E = (const int*)d_in[1];
  const float* emb = (const float*)d_in[2];
  const float* W1 = (const float*)d_in[3];
  const float* W2 = (const float*)d_in[4];
  const float* bn1g = (const float*)d_in[5];
  const float* bn1b = (const float*)d_in[6];
  const float* bn2g = (const float*)d_in[7];
  const float* bn2b = (const float*)d_in[8];
  const float* rW1 = (const float*)d_in[9];
  const float* rb1 = (const float*)d_in[10];
  const float* rW2 = (const float*)d_in[11];
  const float* rb2 = (const float*)d_in[12];
  float* outp = (float*)d_out;

  char* ws = (char*)d_ws;
  float* P = (float*)(ws + OFF_P);
  float* Q = (float*)(ws + OFF_Q);
  float* R = (float*)(ws + OFF_R);
  int* csr = (int*)(ws + OFF_CSR);
  int* rp = (int*)(ws + OFF_RP);
  int* cnt = (int*)(ws + OFF_CNT);
  int* bs = (int*)(ws + OFF_BS);
  int* flag = (int*)(ws + OFF_FLG);
  float* SS = (float*)(ws + OFF_SS);
  int* SCT = (int*)(ws + OFF_SCT);
  float* ac = (float*)(ws + OFF_AC);
  float* ee = (float*)(ws + OFF_E);
  short* wsp = (short*)(ws + OFF_WSP);
  __half* h1 = (__half*)P;
  __half* h2 = (__half*)((char*)P + SZ_H16);
  __half* h3 = (__half*)R;
  float* part = R;                 // 1.07 MB, time-shared with h3
  int* a01 = (int*)((char*)P + (4 << 20));
  float* momp = (float*)((char*)P + (8 << 20));

  hipMemsetAsync(ws + OFF_ZZ, 0, ZZ_BYTES, stream);
  k_detect<<<1, 64, 0, stream>>>(E, flag);
  k_hist<<<SC_CHUNKS * 8, 256, 0, stream>>>(E, flag, cnt);
  k_scan1<<<NB_SCAN, 256, 0, stream>>>(cnt, rp, bs);
  k_scan2<<<1, 128, 0, stream>>>(bs);
  k_scan3<<<NB_SCAN, 256, 0, stream>>>(rp, bs, cnt);
  k_scatter<<<SC_CHUNKS * 8, 256, 0, stream>>>(E, flag, x, cnt, csr);
  k_prep<<<1, 256, 0, stream>>>(emb, W1, rW1, ee);
  k_prepw<<<512, 256, 0, stream>>>(W1, W2, rW1, wsp);

  float* a1 = ac + 0 * 256, *c1 = a1 + HID;
  float* a2 = ac + 1 * 256, *c2 = a2 + HID;

  // ---- layer 1 (rank-2 shortcut; u1 expanded inside the GEMM) ----
  k_cnt<<<NBC, 256, 0, stream>>>(x, rp, csr, a01, momp);
  k_bnmom<<<1, 128, 0, stream>>>(momp, ee, bn1g, bn1b, a1, c1);
  k_gemm<2, 0><<<NBLK, 256, 0, stream>>>(Q, wsp + 0 * 32768, a1, c1, Q, part,
                                         a01, ee);
  k_bnstat<<<64, 256, 0, stream>>>(part, bn2g, bn2b, a2, c2, SS + 0 * 256, SCT + 0);
  k_act<<<2048, 256, 0, stream>>>(Q, a2, c2, h1);

  // ---- layers 2,3 ----
  int inst = 1;
  for (int i = 1; i < 3; ++i) {
    float* b1a = ac + (2 * i) * 256, *b1c = b1a + HID;
    float* b2a = ac + (2 * i + 1) * 256, *b2c = b2a + HID;
    const int s1 = (i == 1) ? 1 : 3;  // W1[i] slot
    const __half* hin = (i == 1) ? h1 : h2;
    k_agg<<<NN / 4, 256, 0, stream>>>(hin, rp, csr, Q);
    k_gemm<0, 0><<<NBLK, 256, 0, stream>>>(Q, wsp + (size_t)s1 * 32768,
                                           nullptr, nullptr, Q, part, nullptr,
                                           nullptr);
    k_bnstat<<<64, 256, 0, stream>>>(part, bn1g + i * HID, bn1b + i * HID, b1a,
                                     b1c, SS + inst * 256, SCT + inst);
    ++inst;
    k_gemm<1, 0><<<NBLK, 256, 0, stream>>>(Q, wsp + (size_t)(s1 + 1) * 32768,
                                           b1a, b1c, Q, part, nullptr, nullptr);
    k_bnstat<<<64, 256, 0, stream>>>(part, bn2g + i * HID, bn2b + i * HID, b2a,
                                     b2c, SS + inst * 256, SCT + inst);
    ++inst;
    k_act<<<2048, 256, 0, stream>>>(Q, b2a, b2c, (i == 1) ? h2 : h3);
  }

  // ---- fused readout GEMM over [h1|h2|h3] + rank-2 rep0 bias ----
  k_rdgemm<<<NBLK, 256, 0, stream>>>(h1, h2, h3, wsp + (size_t)5 * 32768, x, ee,
                                     rb1, rW2, rb2, outp);
}